// Round 15
// baseline (311.832 us; speedup 1.0000x reference)
//
#include <hip/hip_runtime.h>

#define NB 128
#define NS 100
#define NPRED 24
#define NHID 256
#define NSTEPS 16
#define NCTX 96
// R15: 800 blocks x 512 thr (8 waves = 1 group of 16 rows). Wave w owns
// hidden ch [32w,32w+32): w2 slice = 16 frags = 64 regs -> total <=128
// regs/wave -> 4 waves/SIMD (vs R12's 2). Layer 3: wave w's h2 IS k-chunk w
// -> no h2 exchange; dt-scaled packed vpk partial reduce (R14-proven).
// 2 barriers/step. All frag images / numerics identical to R12/R14.

typedef float f32x4 __attribute__((ext_vector_type(4)));
typedef short bf16x8 __attribute__((ext_vector_type(8)));

__device__ __forceinline__ unsigned short f2bf(float f) {
    union { float f; unsigned u; } v; v.f = f;
    return (unsigned short)((v.u + 0x7fffu + ((v.u >> 16) & 1u)) >> 16);
}
// 1-op RNE pack. ONLY on VALU-produced values (never raw MFMA dst) [R11].
__device__ __forceinline__ unsigned cvtpk(float lo, float hi) {
    unsigned r;
    asm("v_cvt_pk_bf16_f32 %0, %1, %2" : "=v"(r) : "v"(lo), "v"(hi));
    return r;
}
__device__ __forceinline__ bf16x8 mk8(unsigned a, unsigned b, unsigned c, unsigned d) {
    union { unsigned u[4]; bf16x8 v; } x;
    x.u[0] = a; x.u[1] = b; x.u[2] = c; x.u[3] = d;
    return x.v;
}
__device__ __forceinline__ f32x4 bf4_to_f32x4(const unsigned short* pA) {
    uint2 uu = *(const uint2*)pA;
    union { unsigned u; float f; } c0, c1, c2, c3;
    c0.u = uu.x << 16; c1.u = uu.x & 0xffff0000u;
    c2.u = uu.y << 16; c3.u = uu.y & 0xffff0000u;
    f32x4 r; r.x = c0.f; r.y = c1.f; r.z = c2.f; r.w = c3.f;
    return r;
}
__device__ __forceinline__ f32x4 up4(unsigned a, unsigned b) {
    union { unsigned u; float f; } c0, c1, c2, c3;
    c0.u = a << 16; c1.u = a & 0xffff0000u;
    c2.u = b << 16; c3.u = b & 0xffff0000u;
    f32x4 r; r.x = c0.f; r.y = c1.f; r.z = c2.f; r.w = c3.f;
    return r;
}
__device__ __forceinline__ f32x4 relu4(f32x4 a) {
    a.x = fmaxf(a.x, 0.f); a.y = fmaxf(a.y, 0.f);
    a.z = fmaxf(a.z, 0.f); a.w = fmaxf(a.w, 0.f);
    return a;
}

// k-slot permutation within a 32-wide k-block at (lane l, elem e):
//   k_local = 16*(e>>2) + 4*(l>>4) + (e&3)
// Applied identically to A and B fragments (numerically verified R2-R14).

// prep -> d_ws (ushorts): W1F [0,8192) | W3F [8192,16384) | W2F [16384,81920)
__global__ void prep_kernel(const float* __restrict__ W1,
                            const float* __restrict__ W2,
                            const float* __restrict__ W3,
                            unsigned short* __restrict__ wsf) {
    int i = blockIdx.x * 256 + threadIdx.x;   // 0..81919
    if (i < 8192) {
        int T = i >> 9, ll = (i >> 3) & 63, e = i & 7;
        int k = 16 * (e >> 2) + 4 * (ll >> 4) + (e & 3);
        int m = 16 * T + (ll & 15);
        wsf[i] = (k <= 24) ? f2bf(W1[k * NHID + m]) : (unsigned short)0;
    } else if (i < 16384) {
        int idx = i - 8192;
        int ks = idx >> 10, T = (idx >> 9) & 1, ll = (idx >> 3) & 63, e = idx & 7;
        int k = 32 * ks + 16 * (e >> 2) + 4 * (ll >> 4) + (e & 3);
        int m = 16 * T + (ll & 15);
        wsf[i] = (m < NPRED) ? f2bf(W3[k * NPRED + m]) : (unsigned short)0;
    } else {
        int idx = i - 16384;
        int ks = idx >> 13, T = (idx >> 9) & 15, ll = (idx >> 3) & 63, e = idx & 7;
        int k = 32 * ks + 16 * (e >> 2) + 4 * (ll >> 4) + (e & 3);
        int m = 16 * T + (ll & 15);
        wsf[i] = f2bf(W2[k * NHID + m]);
    }
}

__global__ __launch_bounds__(512, 4) void fm_kernel(
    const float* __restrict__ past_target,
    const float* __restrict__ z0g,
    const float* __restrict__ W1, const float* __restrict__ b1,
    const float* __restrict__ b2, const float* __restrict__ b3,
    const unsigned short* __restrict__ wsf,
    float* __restrict__ out) {
    __shared__ __attribute__((aligned(16))) unsigned short cbF[4096]; // 8 KB
    __shared__ __attribute__((aligned(16))) unsigned exA[2048];       // 8 KB h1
    __shared__ __attribute__((aligned(16))) unsigned vpk[2048];       // 8 KB v
    __shared__ float locS[16];

    const int tid = threadIdx.x;   // 0..511
    const int g = blockIdx.x;      // row-group 0..799

    // ---- one-time: fp32 cbias -> bf16 C-frags (16 rows x 32 ch-chunks) ----
    {
        const int r = tid >> 5, c = tid & 31;   // row 0..15, 8-ch chunk 0..31
        const int bb = (g * 16 + r) & 127;
        const float* ctxp = past_target + bb * NCTX;
        float asum = 0.f;
        for (int k = 0; k < NCTX; k++) asum += fabsf(ctxp[k]);
        float loc = fmaxf(asum * (1.f / (float)NCTX), 1e-6f);
        if (c == 0) locS[r] = loc;
        float inv = 1.f / loc;
        f32x4 acc[2];
        const float* b1p = b1 + 8 * c;
#pragma unroll
        for (int u = 0; u < 2; u++) acc[u] = *(const f32x4*)(b1p + 4 * u);
        for (int k = 0; k < NCTX; k++) {
            float sx = ctxp[k] * inv;
            const f32x4* wr = (const f32x4*)(W1 + (26 + k) * NHID + 8 * c);
#pragma unroll
            for (int u = 0; u < 2; u++) {
                f32x4 w = wr[u];
                acc[u].x += sx * w.x; acc[u].y += sx * w.y;
                acc[u].z += sx * w.z; acc[u].w += sx * w.w;
            }
        }
        // C-frag layout: ch 16T+4qq+ii -> cbF[T*256 + qq*64 + r*4 + ii]
        const int T = c >> 1;
#pragma unroll
        for (int u = 0; u < 2; u++) {
            int qq = 2 * (c & 1) + u;
            int base = T * 256 + qq * 64 + r * 4;
            cbF[base + 0] = f2bf(acc[u].x);
            cbF[base + 1] = f2bf(acc[u].y);
            cbF[base + 2] = f2bf(acc[u].z);
            cbF[base + 3] = f2bf(acc[u].w);
        }
    }

    const int w = tid >> 6;          // wave 0..7: owns hidden ch [32w,32w+32)
    const int l = tid & 63;
    const int q = l >> 4, p = l & 15;
    const int R = g * 16 + p;
    const int s = R >> 7, b = R & 127;
    const int l8 = l * 8;

    // ---- persistent registers (target <=128 total) ----
    bf16x8 w1r[2];                   // W1 A-frags (tiles 2w,2w+1): 8 regs
    bf16x8 w2r[16];                  // W2 A-frags (8 ks x 2 tiles): 64 regs
#pragma unroll
    for (int tt = 0; tt < 2; tt++)
        w1r[tt] = *(const bf16x8*)(wsf + (2 * w + tt) * 512 + l8);
#pragma unroll
    for (int ks = 0; ks < 8; ks++)
#pragma unroll
        for (int tt = 0; tt < 2; tt++)
            w2r[2 * ks + tt] = *(const bf16x8*)(wsf + 16384 + (ks * 16 + 2 * w + tt) * 512 + l8);

    // biases packed bf16
    unsigned b2p[4];
#pragma unroll
    for (int tt = 0; tt < 2; tt++) {
        int ch = (2 * w + tt) * 16 + 4 * q;
        b2p[2 * tt]     = cvtpk(b2[ch], b2[ch + 1]);
        b2p[2 * tt + 1] = cvtpk(b2[ch + 2], b2[ch + 3]);
    }
    const float dt = 1.f / (float)NSTEPS;
    unsigned dtb3p[4];
    {
        f32x4 b3f0 = *(const f32x4*)(b3 + 4 * q);
        f32x4 b3f1 = {0.f, 0.f, 0.f, 0.f};
        if (q < 2) b3f1 = *(const f32x4*)(b3 + 16 + 4 * q);
        f32x4 d0 = b3f0 * dt, d1 = b3f1 * dt;
        dtb3p[0] = cvtpk(d0.x, d0.y); dtb3p[1] = cvtpk(d0.z, d0.w);
        dtb3p[2] = cvtpk(d1.x, d1.y); dtb3p[3] = cvtpk(d1.z, d1.w);
    }

    // ---- z state (replicated across the 8 waves; fixed-order math) ----
    f32x4 zs0, zs1;
    {
        const f32x4* zr = (const f32x4*)(z0g + R * NPRED);
        zs0 = zr[q];
        f32x4 zz = {0.f, 0.f, 0.f, 0.f};
        zs1 = zz;
        if (q < 2) zs1 = zr[4 + q];
    }

    __syncthreads();   // cbF + locS ready

    f32x4 cbr[2];
#pragma unroll
    for (int tt = 0; tt < 2; tt++)
        cbr[tt] = bf4_to_f32x4(cbF + (2 * w + tt) * 256 + q * 64 + p * 4);

#pragma unroll 1
    for (int step = 0; step < NSTEPS; step++) {
        // early-issue own W3 frags (k-chunk w; L2-resident; laundered)
        const unsigned short* w3p = wsf + 8192 + (2 * w) * 512 + l8;
        asm volatile("" : "+v"(w3p));
        bf16x8 w3f0 = *(const bf16x8*)(w3p);
        bf16x8 w3f1 = *(const bf16x8*)(w3p + 512);

        float t = 1.f - (float)step * dt;
        float z10 = (q == 2) ? t : zs1.x;   // channel 24 carries t
        bf16x8 bz = mk8(cvtpk(zs0.x, zs0.y), cvtpk(zs0.z, zs0.w),
                        cvtpk(z10, zs1.y), cvtpk(zs1.z, zs1.w));

        // ---- layer 1 (own 32 ch): 2 MFMA -> exA words 4w..4w+3 ----
#pragma unroll
        for (int tt = 0; tt < 2; tt++) {
            f32x4 h = relu4(__builtin_amdgcn_mfma_f32_16x16x32_bf16(w1r[tt], bz, cbr[tt], 0, 0, 0));
            exA[(4 * w + 2 * tt) * 64 + l]     = cvtpk(h.x, h.y);
            exA[(4 * w + 2 * tt + 1) * 64 + l] = cvtpk(h.z, h.w);
        }
        __syncthreads();   // bar1: h1 exchange complete

        // ---- layer 2 (own 32 ch, K=256): 16 MFMA, weights in regs ----
        f32x4 a0 = {0.f, 0.f, 0.f, 0.f}, a1 = a0;
#pragma unroll
        for (int ks = 0; ks < 8; ks++) {
            bf16x8 bb = mk8(exA[(4 * ks) * 64 + l], exA[(4 * ks + 1) * 64 + l],
                            exA[(4 * ks + 2) * 64 + l], exA[(4 * ks + 3) * 64 + l]);
            a0 = __builtin_amdgcn_mfma_f32_16x16x32_bf16(w2r[2 * ks], bb, a0, 0, 0, 0);
            a1 = __builtin_amdgcn_mfma_f32_16x16x32_bf16(w2r[2 * ks + 1], bb, a1, 0, 0, 0);
        }
        // bias + relu + pack own h2 = k-chunk w B-frag (lane-local)
        unsigned bh2[4];
        {
            f32x4 h0 = relu4(a0 + up4(b2p[0], b2p[1]));
            f32x4 h1 = relu4(a1 + up4(b2p[2], b2p[3]));
            bh2[0] = cvtpk(h0.x, h0.y); bh2[1] = cvtpk(h0.z, h0.w);
            bh2[2] = cvtpk(h1.x, h1.y); bh2[3] = cvtpk(h1.z, h1.w);
        }

        // ---- layer 3 partial (own k-chunk w): 2 MFMA, no h2 exchange ----
        f32x4 v0 = {0.f, 0.f, 0.f, 0.f}, v1 = v0;
        {
            bf16x8 bbA = mk8(bh2[0], bh2[1], bh2[2], bh2[3]);
            v0 = __builtin_amdgcn_mfma_f32_16x16x32_bf16(w3f0, bbA, v0, 0, 0, 0);
            v1 = __builtin_amdgcn_mfma_f32_16x16x32_bf16(w3f1, bbA, v1, 0, 0, 0);
        }
        // dt-scale via compiler VALU (hazard-safe on MFMA dst), THEN cvtpk.
        {
            f32x4 vd0 = v0 * dt, vd1 = v1 * dt;
            vpk[(4 * w + 0) * 64 + l] = cvtpk(vd0.x, vd0.y);
            vpk[(4 * w + 1) * 64 + l] = cvtpk(vd0.z, vd0.w);
            vpk[(4 * w + 2) * 64 + l] = cvtpk(vd1.x, vd1.y);
            vpk[(4 * w + 3) * 64 + l] = cvtpk(vd1.z, vd1.w);
        }
        __syncthreads();   // bar2: all 8 partials ready

        // ---- all-reduce in FIXED order (z identical across waves) ----
        f32x4 sv0 = {0.f, 0.f, 0.f, 0.f}, sv1 = sv0;
#pragma unroll
        for (int w2 = 0; w2 < 8; w2++) {
            f32x4 t0 = up4(vpk[(4 * w2 + 0) * 64 + l], vpk[(4 * w2 + 1) * 64 + l]);
            f32x4 t1 = up4(vpk[(4 * w2 + 2) * 64 + l], vpk[(4 * w2 + 3) * 64 + l]);
            sv0.x += t0.x; sv0.y += t0.y; sv0.z += t0.z; sv0.w += t0.w;
            sv1.x += t1.x; sv1.y += t1.y; sv1.z += t1.z; sv1.w += t1.w;
        }

        // ---- Euler: z -= (dt*v_sum + dt*b3) (pads: v==0, dtb3==0) ----
        {
            f32x4 d0 = up4(dtb3p[0], dtb3p[1]), d1 = up4(dtb3p[2], dtb3p[3]);
            zs0.x -= sv0.x + d0.x; zs0.y -= sv0.y + d0.y;
            zs0.z -= sv0.z + d0.z; zs0.w -= sv0.w + d0.w;
            zs1.x -= sv1.x + d1.x; zs1.y -= sv1.y + d1.y;
            zs1.z -= sv1.z + d1.z; zs1.w -= sv1.w + d1.w;
        }
        // no bar: next exA writes safe (readers done pre-bar2); next vpk
        // writes fenced by bar1 of next step.
    }

    // ---- store (wave 0 only) ----
    if (w == 0) {
        float loc = locS[p];
        float* op = out + b * (NS * NPRED) + s * NPRED;
        f32x4 o0 = zs0 * loc;
        *(f32x4*)(op + 4 * q) = o0;
        if (q < 2) { f32x4 o1 = zs1 * loc; *(f32x4*)(op + 16 + 4 * q) = o1; }
    }
}

extern "C" void kernel_launch(void* const* d_in, const int* in_sizes, int n_in,
                              void* d_out, int out_size, void* d_ws, size_t ws_size,
                              hipStream_t stream) {
    const float* past_target = (const float*)d_in[0];
    // d_in[1] past_observed_values: not used by the reference math
    const float* z0 = (const float*)d_in[2];
    const float* W1 = (const float*)d_in[3];
    const float* b1 = (const float*)d_in[4];
    const float* W2 = (const float*)d_in[5];
    const float* b2 = (const float*)d_in[6];
    const float* W3 = (const float*)d_in[7];
    const float* b3 = (const float*)d_in[8];

    unsigned short* wsf = (unsigned short*)d_ws;   // 160 KB frag image (proven)

    prep_kernel<<<320, 256, 0, stream>>>(W1, W2, W3, wsf);
    fm_kernel<<<800, 512, 0, stream>>>(past_target, z0, W1, b1, b2, b3,
                                       wsf, (float*)d_out);
}

// Round 16
// 125.185 us; speedup vs baseline: 2.4910x; 2.4910x over previous
//
#include <hip/hip_runtime.h>

#define NB 128
#define NS 100
#define NPRED 24
#define NHID 256
#define NSTEPS 16
#define NCTX 96
// R16 = R12 skeleton (127us proven, best) + vectorized LDS exchange:
// exA/vred re-laid so each lane's 4 words are contiguous -> ds_read/write_b128
// (15 vector ops/wave/step vs ~80 scalar b32). Numerics identical to R12.
// 800 blocks x 256 thr (4 waves); wave w owns hidden ch [64w,64w+64);
// W1/W2/W3 slices persistent in registers; 2 barriers/step.

typedef float f32x4 __attribute__((ext_vector_type(4)));
typedef short bf16x8 __attribute__((ext_vector_type(8)));

__device__ __forceinline__ unsigned short f2bf(float f) {
    union { float f; unsigned u; } v; v.f = f;
    return (unsigned short)((v.u + 0x7fffu + ((v.u >> 16) & 1u)) >> 16);
}
// 1-op RNE pack. ONLY on VALU-produced values (never raw MFMA dst) [R11].
__device__ __forceinline__ unsigned cvtpk(float lo, float hi) {
    unsigned r;
    asm("v_cvt_pk_bf16_f32 %0, %1, %2" : "=v"(r) : "v"(lo), "v"(hi));
    return r;
}
__device__ __forceinline__ bf16x8 mk8(unsigned a, unsigned b, unsigned c, unsigned d) {
    union { unsigned u[4]; bf16x8 v; } x;
    x.u[0] = a; x.u[1] = b; x.u[2] = c; x.u[3] = d;
    return x.v;
}
__device__ __forceinline__ f32x4 bf4_to_f32x4(const unsigned short* pA) {
    uint2 uu = *(const uint2*)pA;
    union { unsigned u; float f; } c0, c1, c2, c3;
    c0.u = uu.x << 16; c1.u = uu.x & 0xffff0000u;
    c2.u = uu.y << 16; c3.u = uu.y & 0xffff0000u;
    f32x4 r; r.x = c0.f; r.y = c1.f; r.z = c2.f; r.w = c3.f;
    return r;
}
__device__ __forceinline__ f32x4 relu4(f32x4 a) {
    a.x = fmaxf(a.x, 0.f); a.y = fmaxf(a.y, 0.f);
    a.z = fmaxf(a.z, 0.f); a.w = fmaxf(a.w, 0.f);
    return a;
}

// k-slot permutation within a 32-wide k-block at (lane l, elem e):
//   k_local = 16*(e>>2) + 4*(l>>4) + (e&3)
// Applied identically to A and B fragments (numerically verified R2-R14).

// prep -> d_ws (ushorts): W1F [0,8192) | W3F [8192,16384) | W2F [16384,81920)
__global__ void prep_kernel(const float* __restrict__ W1,
                            const float* __restrict__ W2,
                            const float* __restrict__ W3,
                            unsigned short* __restrict__ wsf) {
    int i = blockIdx.x * 256 + threadIdx.x;   // 0..81919
    if (i < 8192) {
        int T = i >> 9, ll = (i >> 3) & 63, e = i & 7;
        int k = 16 * (e >> 2) + 4 * (ll >> 4) + (e & 3);
        int m = 16 * T + (ll & 15);
        wsf[i] = (k <= 24) ? f2bf(W1[k * NHID + m]) : (unsigned short)0;
    } else if (i < 16384) {
        int idx = i - 8192;
        int ks = idx >> 10, T = (idx >> 9) & 1, ll = (idx >> 3) & 63, e = idx & 7;
        int k = 32 * ks + 16 * (e >> 2) + 4 * (ll >> 4) + (e & 3);
        int m = 16 * T + (ll & 15);
        wsf[i] = (m < NPRED) ? f2bf(W3[k * NPRED + m]) : (unsigned short)0;
    } else {
        int idx = i - 16384;
        int ks = idx >> 13, T = (idx >> 9) & 15, ll = (idx >> 3) & 63, e = idx & 7;
        int k = 32 * ks + 16 * (e >> 2) + 4 * (ll >> 4) + (e & 3);
        int m = 16 * T + (ll & 15);
        wsf[i] = f2bf(W2[k * NHID + m]);
    }
}

__global__ __launch_bounds__(256, 2) void fm_kernel(
    const float* __restrict__ past_target,
    const float* __restrict__ z0g,
    const float* __restrict__ W1, const float* __restrict__ b1,
    const float* __restrict__ b2, const float* __restrict__ b3,
    const unsigned short* __restrict__ wsf,
    float* __restrict__ out) {
    __shared__ __attribute__((aligned(16))) unsigned short cbF[4096]; // 8 KB
    // exA: h1 words, vectorized layout: word o (o=0..31) at
    //   exA[(o>>2)*256 + l*4 + (o&3)]  -> lane-contiguous 16B per group
    __shared__ __attribute__((aligned(16))) unsigned exA[2048];       // 8 KB
    // vredV: f32 partials, group (2w+i) at vredV[(2w+i)*256 + l*4 + 0..3]
    __shared__ __attribute__((aligned(16))) float vredV[2048];        // 8 KB

    const int tid = threadIdx.x;
    const int g = blockIdx.x;        // row-group 0..799

    // ---- one-time: fp32 cbias -> bf16 C-frags (16 rows x 16 ch-chunks) ----
    {
        const int r = tid >> 4, c = tid & 15;
        const int bb = (g * 16 + r) & 127;
        const float* ctxp = past_target + bb * NCTX;
        float asum = 0.f;
        for (int k = 0; k < NCTX; k++) asum += fabsf(ctxp[k]);
        float inv = 1.f / fmaxf(asum * (1.f / (float)NCTX), 1e-6f);
        f32x4 acc[4];
        const float* b1p = b1 + 16 * c;
#pragma unroll
        for (int u = 0; u < 4; u++) acc[u] = *(const f32x4*)(b1p + 4 * u);
        for (int k = 0; k < NCTX; k++) {
            float sx = ctxp[k] * inv;
            const f32x4* wr = (const f32x4*)(W1 + (26 + k) * NHID + 16 * c);
#pragma unroll
            for (int u = 0; u < 4; u++) {
                f32x4 w = wr[u];
                acc[u].x += sx * w.x; acc[u].y += sx * w.y;
                acc[u].z += sx * w.z; acc[u].w += sx * w.w;
            }
        }
        // C-frag layout: ch 16T+4qq+ii -> cbF[T*256 + qq*64 + r*4 + ii]
#pragma unroll
        for (int qq = 0; qq < 4; qq++) {
            int base = c * 256 + qq * 64 + r * 4;
            cbF[base + 0] = f2bf(acc[qq].x);
            cbF[base + 1] = f2bf(acc[qq].y);
            cbF[base + 2] = f2bf(acc[qq].z);
            cbF[base + 3] = f2bf(acc[qq].w);
        }
    }

    const int w = tid >> 6;          // wave 0..3: owns hidden ch [64w,64w+64)
    const int l = tid & 63;
    const int q = l >> 4, p = l & 15;
    const int R = g * 16 + p;
    const int s = R >> 7, b = R & 127;
    const int l8 = l * 8;
    const int l4 = l * 4;

    // ---- persistent registers ----
    bf16x8 w1r[4];                   // W1 A-frags: 16 regs
    bf16x8 w2r[32];                  // W2 A-frags: 128 regs
    bf16x8 w3r[4];                   // W3 A-frags own ks=2w,2w+1: 16 regs
#pragma unroll
    for (int j = 0; j < 4; j++)
        w1r[j] = *(const bf16x8*)(wsf + (4 * w + j) * 512 + l8);
#pragma unroll
    for (int ks = 0; ks < 8; ks++)
#pragma unroll
        for (int j = 0; j < 4; j++)
            w2r[ks * 4 + j] = *(const bf16x8*)(wsf + 16384 + (ks * 16 + 4 * w + j) * 512 + l8);
#pragma unroll
    for (int d = 0; d < 2; d++)
#pragma unroll
        for (int tt = 0; tt < 2; tt++)
            w3r[2 * d + tt] = *(const bf16x8*)(wsf + 8192 + (2 * w + d) * 1024 + tt * 512 + l8);

    f32x4 b2f[4];
#pragma unroll
    for (int j = 0; j < 4; j++)
        b2f[j] = *(const f32x4*)(b2 + (4 * w + j) * 16 + 4 * q);
    f32x4 b3f0 = *(const f32x4*)(b3 + 4 * q);
    f32x4 b3f1 = {0.f, 0.f, 0.f, 0.f};
    if (q < 2) b3f1 = *(const f32x4*)(b3 + 16 + 4 * q);

    // ---- z state (replicated across the 4 waves; fixed-order math) ----
    f32x4 zs0, zs1;
    {
        const f32x4* zr = (const f32x4*)(z0g + R * NPRED);
        zs0 = zr[q];
        f32x4 zz = {0.f, 0.f, 0.f, 0.f};
        zs1 = zz;
        if (q < 2) zs1 = zr[4 + q];
    }

    __syncthreads();   // cbF ready

    f32x4 cbr[4];
#pragma unroll
    for (int j = 0; j < 4; j++)
        cbr[j] = bf4_to_f32x4(cbF + (4 * w + j) * 256 + q * 64 + p * 4);

    const float dt = 1.f / (float)NSTEPS;
#pragma unroll 1
    for (int step = 0; step < NSTEPS; step++) {
        float t = 1.f - (float)step * dt;
        float z10 = (q == 2) ? t : zs1.x;   // channel 24 carries t
        // zs/z10 are VALU-produced -> cvtpk safe
        bf16x8 bz = mk8(cvtpk(zs0.x, zs0.y), cvtpk(zs0.z, zs0.w),
                        cvtpk(z10, zs1.y), cvtpk(zs1.z, zs1.w));

        // ---- layer 1 (own 64 ch): 4 MFMA -> exA, two b128 writes ----
        // word o = 8w+2j+u -> group o>>2 = 2w+(j>>1), slot 2(j&1)+u
        {
            f32x4 h0 = relu4(__builtin_amdgcn_mfma_f32_16x16x32_bf16(w1r[0], bz, cbr[0], 0, 0, 0));
            f32x4 h1 = relu4(__builtin_amdgcn_mfma_f32_16x16x32_bf16(w1r[1], bz, cbr[1], 0, 0, 0));
            uint4 t0;
            t0.x = cvtpk(h0.x, h0.y); t0.y = cvtpk(h0.z, h0.w);
            t0.z = cvtpk(h1.x, h1.y); t0.w = cvtpk(h1.z, h1.w);
            *(uint4*)(exA + (2 * w) * 256 + l4) = t0;
            f32x4 h2 = relu4(__builtin_amdgcn_mfma_f32_16x16x32_bf16(w1r[2], bz, cbr[2], 0, 0, 0));
            f32x4 h3 = relu4(__builtin_amdgcn_mfma_f32_16x16x32_bf16(w1r[3], bz, cbr[3], 0, 0, 0));
            uint4 t1;
            t1.x = cvtpk(h2.x, h2.y); t1.y = cvtpk(h2.z, h2.w);
            t1.z = cvtpk(h3.x, h3.y); t1.w = cvtpk(h3.z, h3.w);
            *(uint4*)(exA + (2 * w + 1) * 256 + l4) = t1;
        }
        __syncthreads();   // bar1: h1 exchange complete

        // ---- layer 2 (own 64 ch, K=256): 8 b128 reads + 32 MFMA ----
        f32x4 a0 = {0.f, 0.f, 0.f, 0.f}, a1 = a0, a2 = a0, a3 = a0;
#pragma unroll
        for (int ks = 0; ks < 8; ks++) {
            uint4 bw = *(const uint4*)(exA + ks * 256 + l4);
            bf16x8 bb = mk8(bw.x, bw.y, bw.z, bw.w);
            a0 = __builtin_amdgcn_mfma_f32_16x16x32_bf16(w2r[ks * 4 + 0], bb, a0, 0, 0, 0);
            a1 = __builtin_amdgcn_mfma_f32_16x16x32_bf16(w2r[ks * 4 + 1], bb, a1, 0, 0, 0);
            a2 = __builtin_amdgcn_mfma_f32_16x16x32_bf16(w2r[ks * 4 + 2], bb, a2, 0, 0, 0);
            a3 = __builtin_amdgcn_mfma_f32_16x16x32_bf16(w2r[ks * 4 + 3], bb, a3, 0, 0, 0);
        }
        // bias + relu + pack own h2 (VALU outputs -> cvtpk safe)
        unsigned bh2[8];
        {
            f32x4 h0 = relu4(a0 + b2f[0]), h1 = relu4(a1 + b2f[1]);
            f32x4 h2 = relu4(a2 + b2f[2]), h3 = relu4(a3 + b2f[3]);
            bh2[0] = cvtpk(h0.x, h0.y); bh2[1] = cvtpk(h0.z, h0.w);
            bh2[2] = cvtpk(h1.x, h1.y); bh2[3] = cvtpk(h1.z, h1.w);
            bh2[4] = cvtpk(h2.x, h2.y); bh2[5] = cvtpk(h2.z, h2.w);
            bh2[6] = cvtpk(h3.x, h3.y); bh2[7] = cvtpk(h3.z, h3.w);
        }

        // ---- layer 3 partial (own k-chunks ks=2w,2w+1): 4 MFMA ----
        f32x4 v0 = {0.f, 0.f, 0.f, 0.f}, v1 = v0;
        {
            bf16x8 bbA = mk8(bh2[0], bh2[1], bh2[2], bh2[3]);
            bf16x8 bbB = mk8(bh2[4], bh2[5], bh2[6], bh2[7]);
            v0 = __builtin_amdgcn_mfma_f32_16x16x32_bf16(w3r[0], bbA, v0, 0, 0, 0);
            v1 = __builtin_amdgcn_mfma_f32_16x16x32_bf16(w3r[1], bbA, v1, 0, 0, 0);
            v0 = __builtin_amdgcn_mfma_f32_16x16x32_bf16(w3r[2], bbB, v0, 0, 0, 0);
            v1 = __builtin_amdgcn_mfma_f32_16x16x32_bf16(w3r[3], bbB, v1, 0, 0, 0);
        }
        // f32 partial exchange: two b128 writes (compiler-scheduled ds_write
        // of MFMA dst = hazard-safe, R9/R12-proven path, now vectorized)
        *(f32x4*)(vredV + (2 * w) * 256 + l4) = v0;
        *(f32x4*)(vredV + (2 * w + 1) * 256 + l4) = v1;
        __syncthreads();   // bar2: partials ready

        // ---- all-reduce in FIXED order (z identical across waves) ----
        f32x4 sv0 = {0.f, 0.f, 0.f, 0.f}, sv1 = sv0;
#pragma unroll
        for (int w2 = 0; w2 < 4; w2++) {
            f32x4 t0 = *(const f32x4*)(vredV + (2 * w2) * 256 + l4);
            f32x4 t1 = *(const f32x4*)(vredV + (2 * w2 + 1) * 256 + l4);
            sv0.x += t0.x; sv0.y += t0.y; sv0.z += t0.z; sv0.w += t0.w;
            sv1.x += t1.x; sv1.y += t1.y; sv1.z += t1.z; sv1.w += t1.w;
        }

        // ---- Euler: z -= dt*(v + b3) (pad channels: v==0, b3f==0) ----
        zs0.x -= dt * (sv0.x + b3f0.x); zs0.y -= dt * (sv0.y + b3f0.y);
        zs0.z -= dt * (sv0.z + b3f0.z); zs0.w -= dt * (sv0.w + b3f0.w);
        zs1.x -= dt * (sv1.x + b3f1.x); zs1.y -= dt * (sv1.y + b3f1.y);
        zs1.z -= dt * (sv1.z + b3f1.z); zs1.w -= dt * (sv1.w + b3f1.w);
        // no bar here: next step's exA writes are safe (readers done pre-bar2),
        // next vredV writes are fenced by bar1 of the next step.
    }

    // ---- store (wave 0 only; loc recomputed once) ----
    if (w == 0) {
        const float* ctxl = past_target + b * NCTX;
        float asum = 0.f;
        for (int k = 0; k < NCTX; k++) asum += fabsf(ctxl[k]);
        float loc = fmaxf(asum * (1.f / (float)NCTX), 1e-6f);
        float* op = out + b * (NS * NPRED) + s * NPRED;
        f32x4 o0 = zs0 * loc;
        *(f32x4*)(op + 4 * q) = o0;
        if (q < 2) { f32x4 o1 = zs1 * loc; *(f32x4*)(op + 16 + 4 * q) = o1; }
    }
}

extern "C" void kernel_launch(void* const* d_in, const int* in_sizes, int n_in,
                              void* d_out, int out_size, void* d_ws, size_t ws_size,
                              hipStream_t stream) {
    const float* past_target = (const float*)d_in[0];
    // d_in[1] past_observed_values: not used by the reference math
    const float* z0 = (const float*)d_in[2];
    const float* W1 = (const float*)d_in[3];
    const float* b1 = (const float*)d_in[4];
    const float* W2 = (const float*)d_in[5];
    const float* b2 = (const float*)d_in[6];
    const float* W3 = (const float*)d_in[7];
    const float* b3 = (const float*)d_in[8];

    unsigned short* wsf = (unsigned short*)d_ws;   // 160 KB frag image (proven)

    prep_kernel<<<320, 256, 0, stream>>>(W1, W2, W3, wsf);
    fm_kernel<<<800, 256, 0, stream>>>(past_target, z0, W1, b1, b2, b3,
                                       wsf, (float*)d_out);
}

// Round 17
// 49.774 us; speedup vs baseline: 6.2649x; 2.5151x over previous
//
#include <hip/hip_runtime.h>

#define NB 128
#define NS 100
#define NPRED 24
#define NHID 256
#define NSTEPS 16
#define NCTX 96
// R17 = R16 step loop (125us best, byte-identical) + cbias/loc precomputed
// ONCE per batch row in prep_kernel (was recomputed 100x redundantly per
// block: ~1.2GB L2 traffic + 96-iter FMA loops). d_ws grows to ~225KB:
//   frags [0,163840)B | cbias bf16 [163840,229376)B | loc f32 [229376,229888)B
// fm prologue: 4 direct uint2 reads/lane (cbr) + 1 f32 read at store.

typedef float f32x4 __attribute__((ext_vector_type(4)));
typedef short bf16x8 __attribute__((ext_vector_type(8)));

__device__ __forceinline__ unsigned short f2bf(float f) {
    union { float f; unsigned u; } v; v.f = f;
    return (unsigned short)((v.u + 0x7fffu + ((v.u >> 16) & 1u)) >> 16);
}
// 1-op RNE pack. ONLY on VALU-produced values (never raw MFMA dst) [R11].
__device__ __forceinline__ unsigned cvtpk(float lo, float hi) {
    unsigned r;
    asm("v_cvt_pk_bf16_f32 %0, %1, %2" : "=v"(r) : "v"(lo), "v"(hi));
    return r;
}
__device__ __forceinline__ bf16x8 mk8(unsigned a, unsigned b, unsigned c, unsigned d) {
    union { unsigned u[4]; bf16x8 v; } x;
    x.u[0] = a; x.u[1] = b; x.u[2] = c; x.u[3] = d;
    return x.v;
}
__device__ __forceinline__ f32x4 bf4_to_f32x4(const unsigned short* pA) {
    uint2 uu = *(const uint2*)pA;
    union { unsigned u; float f; } c0, c1, c2, c3;
    c0.u = uu.x << 16; c1.u = uu.x & 0xffff0000u;
    c2.u = uu.y << 16; c3.u = uu.y & 0xffff0000u;
    f32x4 r; r.x = c0.f; r.y = c1.f; r.z = c2.f; r.w = c3.f;
    return r;
}
__device__ __forceinline__ f32x4 relu4(f32x4 a) {
    a.x = fmaxf(a.x, 0.f); a.y = fmaxf(a.y, 0.f);
    a.z = fmaxf(a.z, 0.f); a.w = fmaxf(a.w, 0.f);
    return a;
}

// k-slot permutation within a 32-wide k-block at (lane l, elem e):
//   k_local = 16*(e>>2) + 4*(l>>4) + (e&3)
// Applied identically to A and B fragments (numerically verified R2-R16).

// prep: blocks 0..127 -> cbias/loc for batch row b=blk (computed ONCE,
// same sequential fma order as the old in-kernel prologue -> bit-identical);
// blocks 128..447 -> frag images (R12/R16-proven indexing).
__global__ void prep_kernel(const float* __restrict__ past_target,
                            const float* __restrict__ W1,
                            const float* __restrict__ b1,
                            const float* __restrict__ W2,
                            const float* __restrict__ W3,
                            unsigned short* __restrict__ wsf) {
    int blk = blockIdx.x;
    if (blk < NB) {
        int b = blk, j = threadIdx.x;           // channel 0..255
        const float* ctxp = past_target + b * NCTX;
        float asum = 0.f;
        for (int k = 0; k < NCTX; k++) asum += fabsf(ctxp[k]);
        float loc = fmaxf(asum * (1.f / (float)NCTX), 1e-6f);
        float inv = 1.f / loc;
        if (j == 0) ((float*)(wsf + 114688))[b] = loc;
        float acc = b1[j];
        for (int k = 0; k < NCTX; k++)
            acc += (ctxp[k] * inv) * W1[(26 + k) * NHID + j];
        wsf[81920 + b * NHID + j] = f2bf(acc);
        return;
    }
    int i = (blk - NB) * 256 + threadIdx.x;   // 0..81919
    if (i < 8192) {
        int T = i >> 9, ll = (i >> 3) & 63, e = i & 7;
        int k = 16 * (e >> 2) + 4 * (ll >> 4) + (e & 3);
        int m = 16 * T + (ll & 15);
        wsf[i] = (k <= 24) ? f2bf(W1[k * NHID + m]) : (unsigned short)0;
    } else if (i < 16384) {
        int idx = i - 8192;
        int ks = idx >> 10, T = (idx >> 9) & 1, ll = (idx >> 3) & 63, e = idx & 7;
        int k = 32 * ks + 16 * (e >> 2) + 4 * (ll >> 4) + (e & 3);
        int m = 16 * T + (ll & 15);
        wsf[i] = (m < NPRED) ? f2bf(W3[k * NPRED + m]) : (unsigned short)0;
    } else {
        int idx = i - 16384;
        int ks = idx >> 13, T = (idx >> 9) & 15, ll = (idx >> 3) & 63, e = idx & 7;
        int k = 32 * ks + 16 * (e >> 2) + 4 * (ll >> 4) + (e & 3);
        int m = 16 * T + (ll & 15);
        wsf[i] = f2bf(W2[k * NHID + m]);
    }
}

__global__ __launch_bounds__(256, 2) void fm_kernel(
    const float* __restrict__ z0g,
    const float* __restrict__ b2, const float* __restrict__ b3,
    const unsigned short* __restrict__ wsf,
    float* __restrict__ out) {
    // exA: h1 words, vectorized: word o at exA[(o>>2)*256 + l*4 + (o&3)]
    __shared__ __attribute__((aligned(16))) unsigned exA[2048];       // 8 KB
    // vredV: f32 partials, group (2w+i) at vredV[(2w+i)*256 + l*4 + 0..3]
    __shared__ __attribute__((aligned(16))) float vredV[2048];        // 8 KB

    const int tid = threadIdx.x;
    const int g = blockIdx.x;        // row-group 0..799

    const int w = tid >> 6;          // wave 0..3: owns hidden ch [64w,64w+64)
    const int l = tid & 63;
    const int q = l >> 4, p = l & 15;
    const int R = g * 16 + p;
    const int s = R >> 7, b = R & 127;
    const int l8 = l * 8;
    const int l4 = l * 4;

    // ---- persistent registers ----
    bf16x8 w1r[4];                   // W1 A-frags: 16 regs
    bf16x8 w2r[32];                  // W2 A-frags: 128 regs
    bf16x8 w3r[4];                   // W3 A-frags own ks=2w,2w+1: 16 regs
#pragma unroll
    for (int j = 0; j < 4; j++)
        w1r[j] = *(const bf16x8*)(wsf + (4 * w + j) * 512 + l8);
#pragma unroll
    for (int ks = 0; ks < 8; ks++)
#pragma unroll
        for (int j = 0; j < 4; j++)
            w2r[ks * 4 + j] = *(const bf16x8*)(wsf + 16384 + (ks * 16 + 4 * w + j) * 512 + l8);
#pragma unroll
    for (int d = 0; d < 2; d++)
#pragma unroll
        for (int tt = 0; tt < 2; tt++)
            w3r[2 * d + tt] = *(const bf16x8*)(wsf + 8192 + (2 * w + d) * 1024 + tt * 512 + l8);

    // cbias C-frag slice: 4 direct uint2 reads (bf16 pairs) from ws table
    f32x4 cbr[4];
#pragma unroll
    for (int j = 0; j < 4; j++)
        cbr[j] = bf4_to_f32x4(wsf + 81920 + b * NHID + (4 * w + j) * 16 + 4 * q);

    f32x4 b2f[4];
#pragma unroll
    for (int j = 0; j < 4; j++)
        b2f[j] = *(const f32x4*)(b2 + (4 * w + j) * 16 + 4 * q);
    f32x4 b3f0 = *(const f32x4*)(b3 + 4 * q);
    f32x4 b3f1 = {0.f, 0.f, 0.f, 0.f};
    if (q < 2) b3f1 = *(const f32x4*)(b3 + 16 + 4 * q);

    // ---- z state (replicated across the 4 waves; fixed-order math) ----
    f32x4 zs0, zs1;
    {
        const f32x4* zr = (const f32x4*)(z0g + R * NPRED);
        zs0 = zr[q];
        f32x4 zz = {0.f, 0.f, 0.f, 0.f};
        zs1 = zz;
        if (q < 2) zs1 = zr[4 + q];
    }

    const float dt = 1.f / (float)NSTEPS;
#pragma unroll 1
    for (int step = 0; step < NSTEPS; step++) {
        float t = 1.f - (float)step * dt;
        float z10 = (q == 2) ? t : zs1.x;   // channel 24 carries t
        // zs/z10 are VALU-produced -> cvtpk safe
        bf16x8 bz = mk8(cvtpk(zs0.x, zs0.y), cvtpk(zs0.z, zs0.w),
                        cvtpk(z10, zs1.y), cvtpk(zs1.z, zs1.w));

        // ---- layer 1 (own 64 ch): 4 MFMA -> exA, two b128 writes ----
        {
            f32x4 h0 = relu4(__builtin_amdgcn_mfma_f32_16x16x32_bf16(w1r[0], bz, cbr[0], 0, 0, 0));
            f32x4 h1 = relu4(__builtin_amdgcn_mfma_f32_16x16x32_bf16(w1r[1], bz, cbr[1], 0, 0, 0));
            uint4 t0;
            t0.x = cvtpk(h0.x, h0.y); t0.y = cvtpk(h0.z, h0.w);
            t0.z = cvtpk(h1.x, h1.y); t0.w = cvtpk(h1.z, h1.w);
            *(uint4*)(exA + (2 * w) * 256 + l4) = t0;
            f32x4 h2 = relu4(__builtin_amdgcn_mfma_f32_16x16x32_bf16(w1r[2], bz, cbr[2], 0, 0, 0));
            f32x4 h3 = relu4(__builtin_amdgcn_mfma_f32_16x16x32_bf16(w1r[3], bz, cbr[3], 0, 0, 0));
            uint4 t1;
            t1.x = cvtpk(h2.x, h2.y); t1.y = cvtpk(h2.z, h2.w);
            t1.z = cvtpk(h3.x, h3.y); t1.w = cvtpk(h3.z, h3.w);
            *(uint4*)(exA + (2 * w + 1) * 256 + l4) = t1;
        }
        __syncthreads();   // bar1: h1 exchange complete

        // ---- layer 2 (own 64 ch, K=256): 8 b128 reads + 32 MFMA ----
        f32x4 a0 = {0.f, 0.f, 0.f, 0.f}, a1 = a0, a2 = a0, a3 = a0;
#pragma unroll
        for (int ks = 0; ks < 8; ks++) {
            uint4 bw = *(const uint4*)(exA + ks * 256 + l4);
            bf16x8 bb = mk8(bw.x, bw.y, bw.z, bw.w);
            a0 = __builtin_amdgcn_mfma_f32_16x16x32_bf16(w2r[ks * 4 + 0], bb, a0, 0, 0, 0);
            a1 = __builtin_amdgcn_mfma_f32_16x16x32_bf16(w2r[ks * 4 + 1], bb, a1, 0, 0, 0);
            a2 = __builtin_amdgcn_mfma_f32_16x16x32_bf16(w2r[ks * 4 + 2], bb, a2, 0, 0, 0);
            a3 = __builtin_amdgcn_mfma_f32_16x16x32_bf16(w2r[ks * 4 + 3], bb, a3, 0, 0, 0);
        }
        // bias + relu + pack own h2 (VALU outputs -> cvtpk safe)
        unsigned bh2[8];
        {
            f32x4 h0 = relu4(a0 + b2f[0]), h1 = relu4(a1 + b2f[1]);
            f32x4 h2 = relu4(a2 + b2f[2]), h3 = relu4(a3 + b2f[3]);
            bh2[0] = cvtpk(h0.x, h0.y); bh2[1] = cvtpk(h0.z, h0.w);
            bh2[2] = cvtpk(h1.x, h1.y); bh2[3] = cvtpk(h1.z, h1.w);
            bh2[4] = cvtpk(h2.x, h2.y); bh2[5] = cvtpk(h2.z, h2.w);
            bh2[6] = cvtpk(h3.x, h3.y); bh2[7] = cvtpk(h3.z, h3.w);
        }

        // ---- layer 3 partial (own k-chunks ks=2w,2w+1): 4 MFMA ----
        f32x4 v0 = {0.f, 0.f, 0.f, 0.f}, v1 = v0;
        {
            bf16x8 bbA = mk8(bh2[0], bh2[1], bh2[2], bh2[3]);
            bf16x8 bbB = mk8(bh2[4], bh2[5], bh2[6], bh2[7]);
            v0 = __builtin_amdgcn_mfma_f32_16x16x32_bf16(w3r[0], bbA, v0, 0, 0, 0);
            v1 = __builtin_amdgcn_mfma_f32_16x16x32_bf16(w3r[1], bbA, v1, 0, 0, 0);
            v0 = __builtin_amdgcn_mfma_f32_16x16x32_bf16(w3r[2], bbB, v0, 0, 0, 0);
            v1 = __builtin_amdgcn_mfma_f32_16x16x32_bf16(w3r[3], bbB, v1, 0, 0, 0);
        }
        // f32 partial exchange: two b128 writes (hazard-safe, proven path)
        *(f32x4*)(vredV + (2 * w) * 256 + l4) = v0;
        *(f32x4*)(vredV + (2 * w + 1) * 256 + l4) = v1;
        __syncthreads();   // bar2: partials ready

        // ---- all-reduce in FIXED order (z identical across waves) ----
        f32x4 sv0 = {0.f, 0.f, 0.f, 0.f}, sv1 = sv0;
#pragma unroll
        for (int w2 = 0; w2 < 4; w2++) {
            f32x4 t0 = *(const f32x4*)(vredV + (2 * w2) * 256 + l4);
            f32x4 t1 = *(const f32x4*)(vredV + (2 * w2 + 1) * 256 + l4);
            sv0.x += t0.x; sv0.y += t0.y; sv0.z += t0.z; sv0.w += t0.w;
            sv1.x += t1.x; sv1.y += t1.y; sv1.z += t1.z; sv1.w += t1.w;
        }

        // ---- Euler: z -= dt*(v + b3) (pad channels: v==0, b3f==0) ----
        zs0.x -= dt * (sv0.x + b3f0.x); zs0.y -= dt * (sv0.y + b3f0.y);
        zs0.z -= dt * (sv0.z + b3f0.z); zs0.w -= dt * (sv0.w + b3f0.w);
        zs1.x -= dt * (sv1.x + b3f1.x); zs1.y -= dt * (sv1.y + b3f1.y);
        zs1.z -= dt * (sv1.z + b3f1.z); zs1.w -= dt * (sv1.w + b3f1.w);
        // no bar here: next step's exA writes are safe (readers done pre-bar2),
        // next vredV writes are fenced by bar1 of the next step.
    }

    // ---- store (wave 0 only; loc from ws table) ----
    if (w == 0) {
        float loc = ((const float*)(wsf + 114688))[b];
        float* op = out + b * (NS * NPRED) + s * NPRED;
        f32x4 o0 = zs0 * loc;
        *(f32x4*)(op + 4 * q) = o0;
        if (q < 2) { f32x4 o1 = zs1 * loc; *(f32x4*)(op + 16 + 4 * q) = o1; }
    }
}

extern "C" void kernel_launch(void* const* d_in, const int* in_sizes, int n_in,
                              void* d_out, int out_size, void* d_ws, size_t ws_size,
                              hipStream_t stream) {
    const float* past_target = (const float*)d_in[0];
    // d_in[1] past_observed_values: not used by the reference math
    const float* z0 = (const float*)d_in[2];
    const float* W1 = (const float*)d_in[3];
    const float* b1 = (const float*)d_in[4];
    const float* W2 = (const float*)d_in[5];
    const float* b2 = (const float*)d_in[6];
    const float* W3 = (const float*)d_in[7];
    const float* b3 = (const float*)d_in[8];

    unsigned short* wsf = (unsigned short*)d_ws;   // ~225 KB used

    prep_kernel<<<448, 256, 0, stream>>>(past_target, W1, b1, W2, W3, wsf);
    fm_kernel<<<800, 256, 0, stream>>>(z0, b2, b3, wsf, (float*)d_out);
}